// Round 6
// baseline (53.774 us; speedup 1.0000x reference)
//
#include <hip/hip_runtime.h>
#include <math.h>

#pragma clang fp contract(off)

#define NPIX 1024

// ---------------------------------------------------------------------------
// 9-tap gaussian (sigma=1, lw=4): phi in f64, normalized with numpy's pairwise
// sum order, cast to f32 — matches jnp.asarray(GAUSS_K, float32).
// ---------------------------------------------------------------------------
__device__ __forceinline__ void compute_gk(float gk[9]) {
    double phi[9];
    #pragma unroll
    for (int t = 0; t < 9; ++t) {
        double d = (double)(t - 4);
        phi[t] = exp(-0.5 * d * d);
    }
    double s = (((phi[0] + phi[1]) + (phi[2] + phi[3])) +
                ((phi[4] + phi[5]) + (phi[6] + phi[7]))) + phi[8];
    #pragma unroll
    for (int t = 0; t < 9; ++t) gk[t] = (float)(phi[t] / s);
}

__device__ __forceinline__ float ldz(const float* b, int i, int j) {
    return (i >= 0 && i < 32 && j >= 0 && j < 32) ? b[(i << 5) + j] : 0.0f;
}
__device__ __forceinline__ float ldc(const float* b, int i, int j) {
    i = i < 0 ? 0 : (i > 31 ? 31 : i);
    j = j < 0 ? 0 : (j > 31 ? 31 : j);
    return b[(i << 5) + j];
}

// ---------------------------------------------------------------------------
// Kernel A (1 block): gk -> ws_gk; bleed+1e-12 -> ws_bleed;
// er = erode3x3(mask!=0) & (mag2(batch0) > 0) -> ws_er.  (round-3/5 proven)
// ---------------------------------------------------------------------------
__global__ __launch_bounds__(256) void canny_pre(const float* __restrict__ x,
                                                 const float* __restrict__ mask,
                                                 float* __restrict__ ws_bleed,
                                                 unsigned int* __restrict__ ws_er,
                                                 float* __restrict__ ws_gk) {
    __shared__ float A[NPIX], Bf[NPIX], C[NPIX], D[NPIX], BL[NPIX];
    __shared__ unsigned int er32[32];
    const int tid = threadIdx.x;
    float gk[9];
    compute_gk(gk);
    if (tid < 9) ws_gk[tid] = gk[tid];

    #pragma unroll
    for (int k = 0; k < 4; ++k) { int p = tid + (k << 8); A[p] = mask[p]; }
    if (tid < 32) er32[tid] = 0u;
    __syncthreads();

    #pragma unroll
    for (int k = 0; k < 4; ++k) {
        int p = tid + (k << 8), i = p >> 5, j = p & 31;
        float s = 0.0f;
        #pragma unroll
        for (int t = 0; t < 9; ++t) s = __fmaf_rn(gk[t], ldz(A, i + t - 4, j), s);
        Bf[p] = s;
    }
    __syncthreads();
    #pragma unroll
    for (int k = 0; k < 4; ++k) {
        int p = tid + (k << 8), i = p >> 5, j = p & 31;
        float s = 0.0f;
        #pragma unroll
        for (int t = 0; t < 9; ++t) s = __fmaf_rn(gk[t], ldz(Bf, i, j + t - 4), s);
        BL[p] = s;
        ws_bleed[p] = s + 1e-12f;   // main divides by exactly this value
    }

    bool er2d[4];
    #pragma unroll
    for (int k = 0; k < 4; ++k) {
        int p = tid + (k << 8), i = p >> 5, j = p & 31;
        bool e = true;
        for (int di = -1; di <= 1; ++di)
            for (int dj = -1; dj <= 1; ++dj) {
                int ii = i + di, jj = j + dj;
                e = e && (ii >= 0 && ii < 32 && jj >= 0 && jj < 32) && (A[(ii << 5) + jj] != 0.0f);
            }
        er2d[k] = e;
    }
    __syncthreads();

    #pragma unroll
    for (int k = 0; k < 4; ++k) {
        int p = tid + (k << 8);
        float r = x[p]            * 0.5f + 0.5f;
        float g = x[p + NPIX]     * 0.5f + 0.5f;
        float b = x[p + 2 * NPIX] * 0.5f + 0.5f;
        A[p] = r * 0.299f + g * 0.587f + b * 0.114f;
    }
    __syncthreads();
    #pragma unroll
    for (int k = 0; k < 4; ++k) {
        int p = tid + (k << 8), i = p >> 5, j = p & 31;
        float s = 0.0f;
        #pragma unroll
        for (int t = 0; t < 9; ++t) s = __fmaf_rn(gk[t], ldz(A, i + t - 4, j), s);
        Bf[p] = s;
    }
    __syncthreads();
    #pragma unroll
    for (int k = 0; k < 4; ++k) {
        int p = tid + (k << 8), i = p >> 5, j = p & 31;
        float s = 0.0f;
        #pragma unroll
        for (int t = 0; t < 9; ++t) s = __fmaf_rn(gk[t], ldz(Bf, i, j + t - 4), s);
        A[p] = s;
    }
    __syncthreads();
    #pragma unroll
    for (int k = 0; k < 4; ++k) { int p = tid + (k << 8); A[p] = A[p] / (BL[p] + 1e-12f); }
    __syncthreads();
    #pragma unroll
    for (int k = 0; k < 4; ++k) { int p = tid + (k << 8), i = p >> 5, j = p & 31;
        Bf[p] = ldc(A, i, j + 1) - ldc(A, i, j - 1); }
    __syncthreads();
    #pragma unroll
    for (int k = 0; k < 4; ++k) { int p = tid + (k << 8), i = p >> 5, j = p & 31;
        C[p] = (ldc(Bf, i - 1, j) + 2.0f * ldc(Bf, i, j)) + ldc(Bf, i + 1, j); }
    __syncthreads();
    #pragma unroll
    for (int k = 0; k < 4; ++k) { int p = tid + (k << 8), i = p >> 5, j = p & 31;
        Bf[p] = ldc(A, i + 1, j) - ldc(A, i - 1, j); }
    __syncthreads();
    #pragma unroll
    for (int k = 0; k < 4; ++k) { int p = tid + (k << 8), i = p >> 5, j = p & 31;
        D[p] = (ldc(Bf, i, j - 1) + 2.0f * ldc(Bf, i, j)) + ldc(Bf, i, j + 1); }
    __syncthreads();
    #pragma unroll
    for (int k = 0; k < 4; ++k) {
        int p = tid + (k << 8), i = p >> 5, j = p & 31;
        if (er2d[k]) {
            float m2 = D[p] * D[p] + C[p] * C[p];
            if (m2 > 0.0f) atomicOr(&er32[i], 1u << j);
        }
    }
    __syncthreads();
    if (tid < 32) ws_er[tid] = er32[tid];
}

// ---------------------------------------------------------------------------
// Kernel B: one block per TWO images (float2 across batch -> packed fp32).
// LDS: APAD 40x32 f2 (zero-guard rows), BPAD 32x40 f2 (zero-guard cols),
// MP[2] 34x34 f32 planes (zero-guard ring). NMS scalar per component.
// Hysteresis floods both images in one 64-lane wave (rows 0-31 img0, 32-63 img1).
// ---------------------------------------------------------------------------
__global__ __launch_bounds__(256) void canny_main2(const float* __restrict__ x,
                                                   const float* __restrict__ ws_bleed,
                                                   const unsigned int* __restrict__ ws_er,
                                                   const float* __restrict__ ws_gk,
                                                   float* __restrict__ out, int Bn) {
    __shared__ float2 APAD[40 * 32];    // (i+4)*32 + j
    __shared__ float2 BPAD[32 * 40];    // i*40 + (j+4)
    __shared__ float  MP[2][34 * 34];   // [img][(i+1)*34 + (j+1)]
    __shared__ unsigned int er[32], hi[64], lo[64], fin[64];
    const int tid = threadIdx.x;
    const int b0 = blockIdx.x * 2;
    const int b1 = (b0 + 1 < Bn) ? b0 + 1 : b0;

    float gk[9];
    #pragma unroll
    for (int t = 0; t < 9; ++t) gk[t] = ws_gk[t];

    const float2 z2 = make_float2(0.0f, 0.0f);
    // zero guards
    APAD[tid < 128 ? tid : 1024 + tid] = z2;
    { int r = tid >> 3, c8 = tid & 7; BPAD[r * 40 + c8 + (c8 < 4 ? 0 : 32)] = z2; }
    {
        float* MZ = &MP[0][0];
        #pragma unroll
        for (int t = 0; t < 10; ++t) { int idx = tid + (t << 8); if (idx < 2 * 34 * 34) MZ[idx] = 0.0f; }
    }
    if (tid < 32) er[tid] = ws_er[tid];

    // gray for both images: p = 4*tid .. 4*tid+3
    {
        const float4* x0 = (const float4*)(x + (size_t)b0 * 3 * NPIX);
        const float4* x1 = (const float4*)(x + (size_t)b1 * 3 * NPIX);
        float4 r0 = x0[tid], g0 = x0[tid + 256], c0 = x0[tid + 512];
        float4 r1 = x1[tid], g1 = x1[tid + 256], c1 = x1[tid + 512];
        int p = tid << 2, i = p >> 5, j = p & 31;
        float2* dst = &APAD[((i + 4) << 5) + j];
        dst[0] = make_float2((r0.x * 0.5f + 0.5f) * 0.299f + (g0.x * 0.5f + 0.5f) * 0.587f + (c0.x * 0.5f + 0.5f) * 0.114f,
                             (r1.x * 0.5f + 0.5f) * 0.299f + (g1.x * 0.5f + 0.5f) * 0.587f + (c1.x * 0.5f + 0.5f) * 0.114f);
        dst[1] = make_float2((r0.y * 0.5f + 0.5f) * 0.299f + (g0.y * 0.5f + 0.5f) * 0.587f + (c0.y * 0.5f + 0.5f) * 0.114f,
                             (r1.y * 0.5f + 0.5f) * 0.299f + (g1.y * 0.5f + 0.5f) * 0.587f + (c1.y * 0.5f + 0.5f) * 0.114f);
        dst[2] = make_float2((r0.z * 0.5f + 0.5f) * 0.299f + (g0.z * 0.5f + 0.5f) * 0.587f + (c0.z * 0.5f + 0.5f) * 0.114f,
                             (r1.z * 0.5f + 0.5f) * 0.299f + (g1.z * 0.5f + 0.5f) * 0.587f + (c1.z * 0.5f + 0.5f) * 0.114f);
        dst[3] = make_float2((r0.w * 0.5f + 0.5f) * 0.299f + (g0.w * 0.5f + 0.5f) * 0.587f + (c0.w * 0.5f + 0.5f) * 0.114f,
                             (r1.w * 0.5f + 0.5f) * 0.299f + (g1.w * 0.5f + 0.5f) * 0.587f + (c1.w * 0.5f + 0.5f) * 0.114f);
    }
    __syncthreads();

    // gaussian blur along H: APAD (guarded) -> BPAD interior
    #pragma unroll
    for (int k = 0; k < 4; ++k) {
        int p = tid + (k << 8), i = p >> 5, j = p & 31;
        float2 s = z2;
        #pragma unroll
        for (int t = 0; t < 9; ++t) {
            float2 v = APAD[((i + t) << 5) + j];
            s.x = __fmaf_rn(gk[t], v.x, s.x);
            s.y = __fmaf_rn(gk[t], v.y, s.y);
        }
        BPAD[i * 40 + j + 4] = s;
    }
    __syncthreads();

    // gaussian blur along W + divide by (bleed+1e-12): BPAD -> APAD interior
    #pragma unroll
    for (int k = 0; k < 4; ++k) {
        int p = tid + (k << 8), i = p >> 5, j = p & 31;
        float2 s = z2;
        #pragma unroll
        for (int t = 0; t < 9; ++t) {
            float2 v = BPAD[i * 40 + j + t];
            s.x = __fmaf_rn(gk[t], v.x, s.x);
            s.y = __fmaf_rn(gk[t], v.y, s.y);
        }
        float bl = ws_bleed[p];
        APAD[((i + 4) << 5) + j] = make_float2(s.x / bl, s.y / bl);
    }
    __syncthreads();

    // fused sobel + mag: sm in APAD interior (clamped idx), mag -> MP planes
    float2 jsr[4], isr[4], mr[4];
    const float2* S = &APAD[4 << 5];
    #pragma unroll
    for (int k = 0; k < 4; ++k) {
        int p = tid + (k << 8), i = p >> 5, j = p & 31;
        int im1 = i > 0 ? i - 1 : 0, ip1 = i < 31 ? i + 1 : 31;
        int jm1 = j > 0 ? j - 1 : 0, jp1 = j < 31 ? j + 1 : 31;
        float2 smm = S[(im1 << 5) + jm1], sm0 = S[(im1 << 5) + j], smp = S[(im1 << 5) + jp1];
        float2 s0m = S[(i   << 5) + jm1],                        s0p = S[(i   << 5) + jp1];
        float2 spm = S[(ip1 << 5) + jm1], sp0 = S[(ip1 << 5) + j], spp = S[(ip1 << 5) + jp1];
        float2 jsob, isob, m;
        {   // component 0
            float tm = smp.x - smm.x, t0 = s0p.x - s0m.x, tp = spp.x - spm.x;
            jsob.x = (tm + 2.0f * t0) + tp;
            float um = spm.x - smm.x, u0 = sp0.x - sm0.x, up = spp.x - smp.x;
            isob.x = (um + 2.0f * u0) + up;
            m.x = sqrtf((isob.x * isob.x + jsob.x * jsob.x) + 1e-9f);
        }
        {   // component 1
            float tm = smp.y - smm.y, t0 = s0p.y - s0m.y, tp = spp.y - spm.y;
            jsob.y = (tm + 2.0f * t0) + tp;
            float um = spm.y - smm.y, u0 = sp0.y - sm0.y, up = spp.y - smp.y;
            isob.y = (um + 2.0f * u0) + up;
            m.y = sqrtf((isob.y * isob.y + jsob.y * jsob.y) + 1e-9f);
        }
        jsr[k] = jsob; isr[k] = isob; mr[k] = m;
        int mi = (i + 1) * 34 + (j + 1);
        MP[0][mi] = m.x;
        MP[1][mi] = m.y;
    }
    __syncthreads();

    // Branchless NMS per component; octant = LAST true selector.
    #pragma unroll
    for (int k = 0; k < 4; ++k) {
        int p = tid + (k << 8), i = p >> 5, j = p & 31;
        int base = (i + 1) * 34 + (j + 1);
        bool eb = (er[i] >> j) & 1u;
        bool hq[2], lq[2];
        #pragma unroll
        for (int c = 0; c < 2; ++c) {
            float iv = c ? isr[k].y : isr[k].x;
            float jv = c ? jsr[k].y : jsr[k].x;
            float m  = c ? mr[k].y  : mr[k].x;
            float ai = fabsf(iv), aj = fabsf(jv);
            bool same = (iv >= 0.0f && jv >= 0.0f) || (iv <= 0.0f && jv <= 0.0f);
            bool opp  = (iv <= 0.0f && jv >= 0.0f) || (iv >= 0.0f && jv <= 0.0f);
            bool age  = (ai >= aj), ale = (ai <= aj);
            int oct = (opp && age) ? 3 : (opp && ale) ? 2 : (same && ale) ? 1 : 0;
            float ais = ai > 0.0f ? ai : 1.0f;
            float ajs = aj > 0.0f ? aj : 1.0f;
            float num = (oct == 3 || oct == 0) ? aj : ai;
            float den = (oct == 3) ? ais : (oct == 0) ? (ai + 1e-9f) : ajs;
            float w = num / den;
            float omw = 1.0f - w;
            int p2i = (oct >= 2) ? -1 : 1;
            int p1i = (oct == 0) ? 1 : (oct == 3) ? -1 : 0;
            int p1j = (oct == 1 || oct == 2) ? 1 : 0;
            const float* MC = MP[c];
            float ip = MC[base + p2i * 34 + 1] * w + MC[base + p1i * 34 + p1j] * omw;
            float im = MC[base - p2i * 34 - 1] * w + MC[base - p1i * 34 - p1j] * omw;
            bool lm = (ip <= m) && (im <= m) && eb;
            hq[c] = lm && (m >= 0.2f);
            lq[c] = lm && (m >= 0.1f);
        }
        unsigned long long bh0 = __ballot(hq[0]);
        unsigned long long bl0 = __ballot(lq[0]);
        unsigned long long bh1 = __ballot(hq[1]);
        unsigned long long bl1 = __ballot(lq[1]);
        if ((tid & 63) == 0) {
            int r0 = (k << 3) + ((tid >> 6) << 1);
            hi[r0]          = (unsigned int)bh0;
            hi[r0 + 1]      = (unsigned int)(bh0 >> 32);
            lo[r0]          = (unsigned int)bl0;
            lo[r0 + 1]      = (unsigned int)(bl0 >> 32);
            hi[32 + r0]     = (unsigned int)bh1;
            hi[32 + r0 + 1] = (unsigned int)(bh1 >> 32);
            lo[32 + r0]     = (unsigned int)bl1;
            lo[32 + r0 + 1] = (unsigned int)(bl1 >> 32);
        }
    }
    __syncthreads();

    // hysteresis: both images in one 64-lane flood; rows don't cross the
    // lane-31/32 boundary (separate images).
    if (tid < 64) {
        unsigned int lw  = lo[tid];
        unsigned int cur = hi[tid];
        for (;;) {
            unsigned int sp  = cur | (cur << 1) | (cur >> 1);
            unsigned int upv = (unsigned int)__shfl((int)sp, (tid + 63) & 63, 64);
            if ((tid & 31) == 0) upv = 0u;
            unsigned int dnv = (unsigned int)__shfl((int)sp, (tid + 1) & 63, 64);
            if ((tid & 31) == 31) dnv = 0u;
            unsigned int nxt = (sp | upv | dnv) & lw;
            bool ch = (nxt != cur);
            cur = nxt;
            if (__ballot((int)ch) == 0ull) break;
        }
        fin[tid] = cur;
    }
    __syncthreads();

    // write out both images: float4 per thread each
    {
        int p = tid << 2, i = p >> 5, j = p & 31;
        unsigned int r0w = fin[i], r1w = fin[32 + i];
        float4 o0, o1;
        o0.x = ((r0w >> (j    )) & 1u) ? 1.0f : -1.0f;
        o0.y = ((r0w >> (j + 1)) & 1u) ? 1.0f : -1.0f;
        o0.z = ((r0w >> (j + 2)) & 1u) ? 1.0f : -1.0f;
        o0.w = ((r0w >> (j + 3)) & 1u) ? 1.0f : -1.0f;
        o1.x = ((r1w >> (j    )) & 1u) ? 1.0f : -1.0f;
        o1.y = ((r1w >> (j + 1)) & 1u) ? 1.0f : -1.0f;
        o1.z = ((r1w >> (j + 2)) & 1u) ? 1.0f : -1.0f;
        o1.w = ((r1w >> (j + 3)) & 1u) ? 1.0f : -1.0f;
        ((float4*)(out + (size_t)b0 * NPIX))[tid] = o0;
        if (b1 != b0) ((float4*)(out + (size_t)b1 * NPIX))[tid] = o1;
    }
}

extern "C" void kernel_launch(void* const* d_in, const int* in_sizes, int n_in,
                              void* d_out, int out_size, void* d_ws, size_t ws_size,
                              hipStream_t stream) {
    const float* x    = (const float*)d_in[0];
    const float* mask = (const float*)d_in[1];
    float* out        = (float*)d_out;
    float* ws_bleed   = (float*)d_ws;
    unsigned int* ws_er = (unsigned int*)(ws_bleed + NPIX);
    float* ws_gk      = (float*)(ws_er + 32);
    int Bn = in_sizes[0] / (3 * NPIX);

    hipLaunchKernelGGL(canny_pre, dim3(1), dim3(256), 0, stream, x, mask, ws_bleed, ws_er, ws_gk);
    hipLaunchKernelGGL(canny_main2, dim3((Bn + 1) / 2), dim3(256), 0, stream,
                       x, ws_bleed, ws_er, ws_gk, out, Bn);
}